// Round 3
// baseline (253.348 us; speedup 1.0000x reference)
//
#include <hip/hip_runtime.h>
#include <hip/hip_bf16.h>

// Gated delta-rule recurrent cell, single step. B=128,H=16,Dk=Dv=128.
// R3: barrier-free, LDS-free design exploiting per-column independence:
//   delta[v] = (v[v] - decay*sum_k S[k,v]k[k]) * beta    (column-local)
//   S'[k,v]  = decay*S[k,v] + k[k]*delta[v]
//   out[v]   = decay*sum_k S[k,v]q[k] + (k.q)*delta[v]
// One block per bh (256 thr = 4 waves). Wave w owns columns w*32..w*32+31,
// all 128 rows, in registers (64 floats/thread). lane = kg*4+vg:
// kg in [0,16) -> rows kg*8..+7 ; vg in [0,4) -> cols base w*32+vg*8 (2xfloat4).
// Column sums finished with 4 __shfl_xor steps over the kg bits (4,8,16,32).
// No __syncthreads anywhere -> waves dephase, memory port stays busy.

#define DK 128
#define DV 128

__global__ __launch_bounds__(256, 4) void s1_cell_kernel(
    const float* __restrict__ q,
    const float* __restrict__ k,
    const float* __restrict__ v,
    const float* __restrict__ g,
    const float* __restrict__ beta,
    const float* __restrict__ S,
    float* __restrict__ out,
    int BH)
{
    const int bh = blockIdx.x;
    const int t  = threadIdx.x;
    const int w  = t >> 6;          // wave 0..3
    const int l  = t & 63;
    const int kg = l >> 2;          // 0..15  (row group)
    const int vg = l & 3;           // 0..3   (col group)
    const int vb = w * 32 + vg * 8; // this thread's 8 columns
    const int kb = kg * 8;          // this thread's 8 rows

    const size_t stile = (size_t)bh * DK * DV;
    const float* __restrict__ Sb = S + stile + (size_t)kb * DV + vb;
    float* __restrict__ So       = out + (size_t)BH * DV + stile + (size_t)kb * DV + vb;
    float* __restrict__ out_o    = out + (size_t)bh * DV;

    // per-thread slices of k,q (rows kb..kb+7) and v (cols vb..vb+7)
    const float4* kp = (const float4*)(k + bh * DK + kb);
    const float4* qp = (const float4*)(q + bh * DK + kb);
    const float4* vp = (const float4*)(v + bh * DV + vb);

    // issue state loads first: 16 independent float4 loads
    float4 s0[8], s1[8];
    #pragma unroll
    for (int i = 0; i < 8; ++i) {
        s0[i] = *(const float4*)(Sb + (size_t)i * DV);
        s1[i] = *(const float4*)(Sb + (size_t)i * DV + 4);
    }

    float4 kA = kp[0], kB = kp[1];
    float4 qA = qp[0], qB = qp[1];
    float kr[8] = {kA.x, kA.y, kA.z, kA.w, kB.x, kB.y, kB.z, kB.w};
    float qr[8] = {qA.x, qA.y, qA.z, qA.w, qB.x, qB.y, qB.z, qB.w};

    const float decay = expf(g[bh]);
    const float bta   = beta[bh];

    // partial column sums over this thread's 8 rows
    float a[8] = {0,0,0,0,0,0,0,0};   // S^T k
    float b[8] = {0,0,0,0,0,0,0,0};   // S^T q
    float kq = 0.f;
    #pragma unroll
    for (int i = 0; i < 8; ++i) {
        const float kv = kr[i], qv = qr[i];
        a[0] += s0[i].x * kv; a[1] += s0[i].y * kv;
        a[2] += s0[i].z * kv; a[3] += s0[i].w * kv;
        a[4] += s1[i].x * kv; a[5] += s1[i].y * kv;
        a[6] += s1[i].z * kv; a[7] += s1[i].w * kv;
        b[0] += s0[i].x * qv; b[1] += s0[i].y * qv;
        b[2] += s0[i].z * qv; b[3] += s0[i].w * qv;
        b[4] += s1[i].x * qv; b[5] += s1[i].y * qv;
        b[6] += s1[i].z * qv; b[7] += s1[i].w * qv;
        kq   += kv * qv;
    }

    // butterfly over kg (lane bits 2..5): masks 4,8,16,32
    #pragma unroll
    for (int m = 4; m <= 32; m <<= 1) {
        #pragma unroll
        for (int j = 0; j < 8; ++j) {
            a[j] += __shfl_xor(a[j], m, 64);
            b[j] += __shfl_xor(b[j], m, 64);
        }
        kq += __shfl_xor(kq, m, 64);
    }

    // delta + out for this thread's 8 columns (all kg lanes compute; kg==0 writes out)
    float4 v0 = vp[0], v1 = vp[1];
    float d[8];
    d[0] = (v0.x - decay * a[0]) * bta;
    d[1] = (v0.y - decay * a[1]) * bta;
    d[2] = (v0.z - decay * a[2]) * bta;
    d[3] = (v0.w - decay * a[3]) * bta;
    d[4] = (v1.x - decay * a[4]) * bta;
    d[5] = (v1.y - decay * a[5]) * bta;
    d[6] = (v1.z - decay * a[6]) * bta;
    d[7] = (v1.w - decay * a[7]) * bta;

    if (kg == 0) {
        float4 o0, o1;
        o0.x = decay * b[0] + kq * d[0];
        o0.y = decay * b[1] + kq * d[1];
        o0.z = decay * b[2] + kq * d[2];
        o0.w = decay * b[3] + kq * d[3];
        o1.x = decay * b[4] + kq * d[4];
        o1.y = decay * b[5] + kq * d[5];
        o1.z = decay * b[6] + kq * d[6];
        o1.w = decay * b[7] + kq * d[7];
        *(float4*)(out_o + vb)     = o0;
        *(float4*)(out_o + vb + 4) = o1;
    }

    // rewrite state: S' = decay*S + k[row]*delta[col]
    #pragma unroll
    for (int i = 0; i < 8; ++i) {
        const float kv = kr[i];
        float4 r0, r1;
        r0.x = decay * s0[i].x + kv * d[0];
        r0.y = decay * s0[i].y + kv * d[1];
        r0.z = decay * s0[i].z + kv * d[2];
        r0.w = decay * s0[i].w + kv * d[3];
        r1.x = decay * s1[i].x + kv * d[4];
        r1.y = decay * s1[i].y + kv * d[5];
        r1.z = decay * s1[i].z + kv * d[6];
        r1.w = decay * s1[i].w + kv * d[7];
        *(float4*)(So + (size_t)i * DV)     = r0;
        *(float4*)(So + (size_t)i * DV + 4) = r1;
    }
}

extern "C" void kernel_launch(void* const* d_in, const int* in_sizes, int n_in,
                              void* d_out, int out_size, void* d_ws, size_t ws_size,
                              hipStream_t stream) {
    const float* q    = (const float*)d_in[0];
    const float* k    = (const float*)d_in[1];
    const float* v    = (const float*)d_in[2];
    const float* g    = (const float*)d_in[3];
    const float* beta = (const float*)d_in[4];
    const float* S    = (const float*)d_in[5];
    float* out = (float*)d_out;

    const int BH = in_sizes[3];   // g has B*H = 2048 elements

    s1_cell_kernel<<<BH, 256, 0, stream>>>(q, k, v, g, beta, S, out, BH);
}